// Round 1
// baseline (613.925 us; speedup 1.0000x reference)
//
#include <hip/hip_runtime.h>
#include <math.h>

#define B_  2048
#define T_  200
#define D_  64
#define H1_ 80
#define H2_ 40

// One workgroup (256 threads) per batch element b.
// Key algebra: info@W1 = q@(W1a+W1c) + k@(W1b - W1c + diag(q)W1d)
//   base1[j] = b1[j] + sum_i q_i (W1[i][j] + W1[128+i][j])         (per b)
//   Wq[i][j] = W1[64+i][j] - W1[128+i][j] + q_i * W1[192+i][j]     (per b, LDS)
//   h1_pre[t][j] = base1[j] + sum_i k[t][i] * Wq[i][j]             (per t, K=64)
__global__ __launch_bounds__(256, 3)
void att_kernel(const float* __restrict__ q,
                const float* __restrict__ k,
                const float* __restrict__ v,
                const float* __restrict__ W1,
                const float* __restrict__ b1,
                const float* __restrict__ a1,
                const float* __restrict__ W2,
                const float* __restrict__ b2,
                const float* __restrict__ a2,
                const float* __restrict__ Wf,
                const float* __restrict__ bf,
                float* __restrict__ out)
{
    const int b   = blockIdx.x;
    const int tid = threadIdx.x;

    __shared__ float lds_q[64];
    __shared__ float lds_wq[64 * 80];      // 20 KB, broadcast reads
    __shared__ float lds_w2[80 * 40];      // 12.8 KB, broadcast reads
    __shared__ float lds_kc[200 * 17];     // 13.6 KB, pad 17 -> conflict-free
    __shared__ float lds_base1[80];
    __shared__ float lds_b2[40];
    __shared__ float lds_wf[40];
    __shared__ float lds_red[256];
    __shared__ float lds_w[256];
    __shared__ float lds_acc[256];

    const float* kb = k + (size_t)b * T_ * D_;
    const float* vb = v + (size_t)b * T_ * D_;

    // ---- phase 0: small loads
    if (tid < 64) lds_q[tid] = q[b * 64 + tid];
    if (tid < 40) { lds_b2[tid] = b2[tid]; lds_wf[tid] = Wf[tid]; }
    __syncthreads();

    // ---- phase 1: build per-b Wq, base1; stage W2
    for (int idx = tid; idx < 64 * 80; idx += 256) {
        int i = idx / 80, j = idx - i * 80;
        lds_wq[idx] = W1[(64 + i) * 80 + j] - W1[(128 + i) * 80 + j]
                    + lds_q[i] * W1[(192 + i) * 80 + j];
    }
    if (tid < 80) {
        float s = b1[tid];
        #pragma unroll 8
        for (int i = 0; i < 64; ++i)
            s += lds_q[i] * (W1[i * 80 + tid] + W1[(128 + i) * 80 + tid]);
        lds_base1[tid] = s;
    }
    for (int idx = tid; idx < 80 * 40; idx += 256) lds_w2[idx] = W2[idx];
    __syncthreads();

    // ---- phase 2: per-t MLP. thread tid handles t = tid (t < 200)
    const int t = tid;
    float h1[H1_];
    #pragma unroll
    for (int j = 0; j < H1_; ++j) h1[j] = lds_base1[j];

    for (int c = 0; c < 4; ++c) {
        const int i0 = c * 16;
        __syncthreads();   // prev chunk consumed
        // stage k[:, i0:i0+16] -> LDS (float4 global loads, coalesced)
        for (int idx = tid; idx < 800; idx += 256) {
            int tr = idx >> 2;
            int ii = (idx & 3) * 4;
            const float4 kv4 = *(const float4*)(kb + tr * 64 + i0 + ii);
            float* dst = &lds_kc[tr * 17 + ii];
            dst[0] = kv4.x; dst[1] = kv4.y; dst[2] = kv4.z; dst[3] = kv4.w;
        }
        __syncthreads();
        if (t < T_) {
            for (int ii = 0; ii < 16; ++ii) {
                const float kv = lds_kc[t * 17 + ii];
                const float4* wq4 = (const float4*)&lds_wq[(i0 + ii) * 80];
                #pragma unroll
                for (int j4 = 0; j4 < 20; ++j4) {
                    float4 w = wq4[j4];
                    h1[j4 * 4 + 0] += kv * w.x;
                    h1[j4 * 4 + 1] += kv * w.y;
                    h1[j4 * 4 + 2] += kv * w.z;
                    h1[j4 * 4 + 3] += kv * w.w;
                }
            }
        }
    }

    float logit = -INFINITY;
    if (t < T_) {
        // PReLU 1 (alpha depends on t)
        const float4* a1p = (const float4*)(a1 + t * H1_);
        #pragma unroll
        for (int j4 = 0; j4 < 20; ++j4) {
            float4 a = a1p[j4];
            float x;
            x = h1[j4 * 4 + 0]; h1[j4 * 4 + 0] = x > 0.f ? x : a.x * x;
            x = h1[j4 * 4 + 1]; h1[j4 * 4 + 1] = x > 0.f ? x : a.y * x;
            x = h1[j4 * 4 + 2]; h1[j4 * 4 + 2] = x > 0.f ? x : a.z * x;
            x = h1[j4 * 4 + 3]; h1[j4 * 4 + 3] = x > 0.f ? x : a.w * x;
        }
        // Dense 2
        float h2[H2_];
        #pragma unroll
        for (int jj = 0; jj < H2_; ++jj) h2[jj] = lds_b2[jj];
        for (int j = 0; j < H1_; ++j) {
            const float hv = h1[j];
            const float4* w2r = (const float4*)&lds_w2[j * 40];
            #pragma unroll
            for (int q4 = 0; q4 < 10; ++q4) {
                float4 w = w2r[q4];
                h2[q4 * 4 + 0] += hv * w.x;
                h2[q4 * 4 + 1] += hv * w.y;
                h2[q4 * 4 + 2] += hv * w.z;
                h2[q4 * 4 + 3] += hv * w.w;
            }
        }
        // PReLU 2 + final dot
        const float4* a2p = (const float4*)(a2 + t * H2_);
        const float4* wf4p = (const float4*)lds_wf;
        float s = bf[0];
        #pragma unroll
        for (int q4 = 0; q4 < 10; ++q4) {
            float4 a  = a2p[q4];
            float4 wf = wf4p[q4];
            float x;
            x = h2[q4 * 4 + 0]; x = x > 0.f ? x : a.x * x; s += x * wf.x;
            x = h2[q4 * 4 + 1]; x = x > 0.f ? x : a.y * x; s += x * wf.y;
            x = h2[q4 * 4 + 2]; x = x > 0.f ? x : a.z * x; s += x * wf.z;
            x = h2[q4 * 4 + 3]; x = x > 0.f ? x : a.w * x; s += x * wf.w;
        }
        logit = s;
    }

    // ---- softmax over t (block-wide)
    lds_red[tid] = logit;
    __syncthreads();
    for (int off = 128; off > 0; off >>= 1) {
        if (tid < off) lds_red[tid] = fmaxf(lds_red[tid], lds_red[tid + off]);
        __syncthreads();
    }
    const float mx = lds_red[0];
    __syncthreads();
    const float ew = (t < T_) ? __expf(logit - mx) : 0.0f;
    lds_red[tid] = ew;
    __syncthreads();
    for (int off = 128; off > 0; off >>= 1) {
        if (tid < off) lds_red[tid] += lds_red[tid + off];
        __syncthreads();
    }
    const float inv = 1.0f / lds_red[0];
    lds_w[tid] = ew * inv;
    __syncthreads();

    // ---- out[b][d] = sum_t w_t * v[b][t][d]
    const int g = tid >> 6, d = tid & 63;
    float acc = 0.0f;
    for (int tt = g; tt < T_; tt += 4)
        acc += lds_w[tt] * vb[tt * 64 + d];
    lds_acc[tid] = acc;
    __syncthreads();
    if (tid < 64)
        out[b * 64 + tid] = lds_acc[tid] + lds_acc[64 + tid]
                          + lds_acc[128 + tid] + lds_acc[192 + tid];
}

extern "C" void kernel_launch(void* const* d_in, const int* in_sizes, int n_in,
                              void* d_out, int out_size, void* d_ws, size_t ws_size,
                              hipStream_t stream) {
    const float* q  = (const float*)d_in[0];
    const float* k  = (const float*)d_in[1];
    const float* v  = (const float*)d_in[2];
    const float* W1 = (const float*)d_in[3];
    const float* b1 = (const float*)d_in[4];
    const float* a1 = (const float*)d_in[5];
    const float* W2 = (const float*)d_in[6];
    const float* b2 = (const float*)d_in[7];
    const float* a2 = (const float*)d_in[8];
    const float* Wf = (const float*)d_in[9];
    const float* bf = (const float*)d_in[10];
    float* out = (float*)d_out;

    hipLaunchKernelGGL(att_kernel, dim3(B_), dim3(256), 0, stream,
                       q, k, v, W1, b1, a1, W2, b2, a2, Wf, bf, out);
}